// Round 6
// baseline (418.211 us; speedup 1.0000x reference)
//
#include <hip/hip_runtime.h>
#include <hip/hip_bf16.h>

#define NB   8
#define CIN  256
#define NN   4096
#define DK   64
#define DOUT 256
#define NT   (NN / 64)          // 64 KV tiles
#define VTILE_BYTES (DOUT * 64 * 2)   // 32 KB per (b, tile)
#define JTOT 384                // 64 Q + 64 K + 256 V output channels

typedef float f32x4 __attribute__((ext_vector_type(4)));
typedef short short8 __attribute__((ext_vector_type(8)));
typedef short short4s __attribute__((ext_vector_type(4)));
typedef int   int2v  __attribute__((ext_vector_type(2)));
typedef int   int4v  __attribute__((ext_vector_type(4)));

__device__ __forceinline__ short f2bf(float f) {
    unsigned u = __builtin_bit_cast(unsigned, f);
    u = (u + 0x7FFFu + ((u >> 16) & 1u)) >> 16;   // RNE
    return (short)u;
}
// pack two f32 -> (bf16(a) | bf16(b)<<16)
__device__ __forceinline__ int pkbf(float a, float b) {
    int r;
    asm("v_cvt_pk_bf16_f32 %0, %1, %2" : "=v"(r) : "v"(a), "v"(b));
    return r;
}

// Swizzled byte offset of element (o, c) inside a 256x64 bf16 V tile.
// Row = 128 B = 8 x 16B chunks; chunk index XORed with (o&7)  [T2 / G4].
// COLUMN PERMUTATION: column c holds tile-local n with c = (n&15)*4 + (n>>4)
// (must match attn's P column order c = lo*4 + mt; both operands permuted
// identically -> PV contraction unchanged).
__device__ __forceinline__ int vtile_byte(int o, int c) {
    return o * 128 + ((((c >> 3) ^ (o & 7)) << 4)) + ((c & 7) << 1);
}

__device__ __forceinline__ void gload_lds16(const void* g, void* l) {
    __builtin_amdgcn_global_load_lds(
        (const __attribute__((address_space(1))) void*)g,
        (__attribute__((address_space(3))) void*)l, 16, 0, 0);
}

// ---------------------------------------------------------------------------
// convw: pack Wq (x 0.125*log2e, folds temperature + exp->exp2), Wk, Wv into
// one bf16 matrix Wb[384][256]. grid 384, block 256.
// ---------------------------------------------------------------------------
__global__ __launch_bounds__(256) void convw_kernel(
    const float* __restrict__ Wq, const float* __restrict__ Wk,
    const float* __restrict__ Wv, short* __restrict__ Wb)
{
    const int j = blockIdx.x;
    const int c = threadIdx.x;
    float v;
    if (j < 64)       v = Wq[j * CIN + c] * 0.18033688011f;   // 0.125*log2(e)
    else if (j < 128) v = Wk[(j - 64) * CIN + c];
    else              v = Wv[(j - 128) * CIN + c];
    Wb[(size_t)j * CIN + c] = f2bf(v);
}

// ---------------------------------------------------------------------------
// Projection via MFMA: Y[j][n] = sum_c Wb[j][c] * x[b][c][n0+n], 64 n x 384 j
// per block. x tile staged to LDS bf16, transposed [n][c] with chunk-XOR
// swizzle ^(n&7). A = Wb rows (global short8), B = x cols (LDS short8).
// D: col=lane&15=n, row=4*hi+r=j.  Q/K: packed short4 stores.
// V: cvt_pk across ntl -> coalesced 8B stores into the permuted+swizzled tile.
// grid (NN/64, NB), block 256 (4 waves x 96 j each).
// ---------------------------------------------------------------------------
__global__ __launch_bounds__(256) void proj_kernel(
    const float* __restrict__ x, const short* __restrict__ Wb,
    short* __restrict__ Qw, short* __restrict__ Kw, short* __restrict__ Vw)
{
    __shared__ short Xt[64][256];            // 32 KB, rows swizzled
    const int t  = threadIdx.x;
    const int nt = blockIdx.x;               // n-tile (also V tile index)
    const int b  = blockIdx.y;
    const int n0 = nt * 64;
    const int w  = t >> 6;
    const int l  = t & 63;
    const int hi = l >> 4, lo = l & 15;

    // ---- stage x tile: thread (l, cg=w) loads 64 c for n = n0+l ----
    {
        const float* xs = x + (size_t)b * CIN * NN + (size_t)(w * 64) * NN + n0 + l;
        #pragma unroll
        for (int c8 = 0; c8 < 8; ++c8) {
            float f[8];
            #pragma unroll
            for (int i = 0; i < 8; ++i)
                f[i] = xs[(size_t)(c8 * 8 + i) * NN];
            int4v pk;
            #pragma unroll
            for (int j = 0; j < 4; ++j) pk[j] = pkbf(f[2 * j], f[2 * j + 1]);
            const int c0 = w * 64 + c8 * 8;
            *(int4v*)((char*)&Xt[0][0] + l * 512 + ((((c0 >> 3) ^ (l & 7)) << 4)))
                = pk;
        }
    }
    __syncthreads();

    const int wj0 = w * 96;                  // wave's j range (6 tiles of 16)
    f32x4 acc[6][4];
    #pragma unroll
    for (int jt = 0; jt < 6; ++jt)
        #pragma unroll
        for (int ntl = 0; ntl < 4; ++ntl) acc[jt][ntl] = f32x4{0.f, 0.f, 0.f, 0.f};

    #pragma unroll 2
    for (int kb = 0; kb < 8; ++kb) {
        short8 aw[6], bx[4];
        #pragma unroll
        for (int jt = 0; jt < 6; ++jt)
            aw[jt] = *(const short8*)(Wb + (size_t)(wj0 + jt * 16 + lo) * CIN
                                         + kb * 32 + hi * 8);
        #pragma unroll
        for (int ntl = 0; ntl < 4; ++ntl) {
            const int n = ntl * 16 + lo;
            bx[ntl] = *(const short8*)((char*)&Xt[0][0] + n * 512
                                       + ((((kb * 4 + hi) ^ (n & 7)) << 4)));
        }
        #pragma unroll
        for (int jt = 0; jt < 6; ++jt)
            #pragma unroll
            for (int ntl = 0; ntl < 4; ++ntl)
                acc[jt][ntl] = __builtin_amdgcn_mfma_f32_16x16x32_bf16(
                    aw[jt], bx[ntl], acc[jt][ntl], 0, 0, 0);
    }

    // ---- epilogue ----
    #pragma unroll
    for (int jt = 0; jt < 6; ++jt) {
        const int jbase = wj0 + jt * 16;     // wave-uniform dest selector
        if (jbase < 128) {                   // Q or K: packed short4 per ntl
            #pragma unroll
            for (int ntl = 0; ntl < 4; ++ntl) {
                const f32x4 a = acc[jt][ntl];
                const int n = ntl * 16 + lo;
                short4s pk;
                #pragma unroll
                for (int r = 0; r < 4; ++r) pk[r] = f2bf(a[r]);
                short* base = (jbase < 64)
                    ? (Qw + (size_t)b * NN * DK + (size_t)(n0 + n) * DK + jbase)
                    : (Kw + (size_t)b * NN * DK + (size_t)(n0 + n) * DK + (jbase - 64));
                *(short4s*)(base + hi * 4) = pk;
            }
        } else {                             // V: pack across ntl -> 8B stores
            char* vtile = (char*)(Vw + (size_t)b * DOUT * NN)
                        + (size_t)nt * VTILE_BYTES;
            #pragma unroll
            for (int r = 0; r < 4; ++r) {
                const int o = jbase - 128 + hi * 4 + r;
                int2v pk;
                pk[0] = pkbf(acc[jt][0][r], acc[jt][1][r]);
                pk[1] = pkbf(acc[jt][2][r], acc[jt][3][r]);
                // column base c = lo*4 (chunk lo>>1, byte (lo&1)*8)
                *(int2v*)(vtile + o * 128 + ((((lo >> 1) ^ (o & 7)) << 4))
                          + ((lo & 1) << 3)) = pk;
            }
        }
    }
}

// ---------------------------------------------------------------------------
// Flash attention: per block 64 q-rows, 4 waves x 16 rows, KVBLK=64.
// V tile double-buffered in LDS (global_load_lds, pre-swizzled+permuted src),
// 2-phase pipeline. Softmax: defer-max (THR=8) + deferred per-lane sum
// (reduced once at end). P packed via cvt_pk -> 4 ds_write_b64 per tile.
// grid (NN/64, NB), block 256.
// NOTE: PV loop MUST be fully unrolled (rule #20: runtime-indexed oacc ->
// scratch; round-2 showed 2.9 GB scratch writes).
// ---------------------------------------------------------------------------
__global__ __launch_bounds__(256) void attn_kernel(
    const short* __restrict__ Q, const short* __restrict__ K,
    const short* __restrict__ Vt, float* __restrict__ out)
{
    __shared__ short Vlds[2][DOUT * 64];     // 2 x 32 KB
    __shared__ short P_lds[4][16][72];       // rows 144 B (16B-aligned)
    const int b  = blockIdx.y;
    const int q0 = blockIdx.x * 64;
    const int w  = threadIdx.x >> 6;
    const int l  = threadIdx.x & 63;
    const int hi = l >> 4, lo = l & 15;

    const short* Qb = Q  + (size_t)b * NN * DK;
    const short* Kb = K  + (size_t)b * NN * DK;
    const char*  Vbase = (const char*)(Vt + (size_t)b * DOUT * NN);

    // Q A-fragments: lane -> row = lane&15, k = (lane>>4)*8 + j (+32 per step)
    const int qrow = q0 + w * 16 + lo;
    const short8 aq0 = *(const short8*)(Qb + (size_t)qrow * DK + hi * 8);
    const short8 aq1 = *(const short8*)(Qb + (size_t)qrow * DK + hi * 8 + 32);

    // per-lane swizzled 16B-chunk offsets for PV ds_reads (o&7 == lo&7)
    const int lo7 = lo & 7;
    const int sw0 = ((hi ^ lo7) << 4);
    const int sw1 = (((4 + hi) ^ lo7) << 4);

    f32x4 oacc[16];
    #pragma unroll
    for (int i = 0; i < 16; ++i) oacc[i] = f32x4{0.f, 0.f, 0.f, 0.f};
    float mrun[4], mthr[4], lpart[4];
    #pragma unroll
    for (int r = 0; r < 4; ++r) { mrun[r] = -1e30f; mthr[r] = -1e29f; lpart[r] = 0.f; }

    // ---- prologue: stage tile 0 into buf 0 ----
    {
        const char* vtile = Vbase;
        #pragma unroll
        for (int kk = 0; kk < 8; ++kk) {
            const int c = kk * 4 + w;                       // 32 chunks of 1 KB
            gload_lds16(vtile + c * 1024 + l * 16,
                        (char*)&Vlds[0][0] + c * 1024);
        }
    }
    asm volatile("s_waitcnt vmcnt(0)" ::: "memory");
    __builtin_amdgcn_s_barrier();
    __builtin_amdgcn_sched_barrier(0);

    for (int t = 0; t < NT; ++t) {
        const int cur = t & 1;
        const int m0  = t * 64;

        // ---- 1. K loads for this tile (issued BEFORE stage: FIFO vmcnt) ----
        short8 bk0[4], bk1[4];
        #pragma unroll
        for (int mt = 0; mt < 4; ++mt) {
            const short* kr = Kb + (size_t)(m0 + mt * 16 + lo) * DK + hi * 8;
            bk0[mt] = *(const short8*)(kr);
            bk1[mt] = *(const short8*)(kr + 32);
        }
        __builtin_amdgcn_sched_barrier(0);

        // ---- 2. STAGE V(t+1) into the other buffer ----
        {
            const int tn = (t + 1 < NT) ? t + 1 : NT - 1;
            const char* vtile = Vbase + (size_t)tn * VTILE_BYTES;
            #pragma unroll
            for (int kk = 0; kk < 8; ++kk) {
                const int c = kk * 4 + w;
                gload_lds16(vtile + c * 1024 + l * 16,
                            (char*)&Vlds[cur ^ 1][0] + c * 1024);
            }
        }
        __builtin_amdgcn_sched_barrier(0);

        // ---- 3. S = Q K^T ----
        f32x4 s[4];
        #pragma unroll
        for (int mt = 0; mt < 4; ++mt) {
            f32x4 acc = {0.f, 0.f, 0.f, 0.f};
            acc = __builtin_amdgcn_mfma_f32_16x16x32_bf16(aq0, bk0[mt], acc, 0, 0, 0);
            acc = __builtin_amdgcn_mfma_f32_16x16x32_bf16(aq1, bk1[mt], acc, 0, 0, 0);
            s[mt] = acc;
        }

        // ---- 4. softmax: defer-max check; rescale only when max grows ----
        float lmax[4];
        #pragma unroll
        for (int r = 0; r < 4; ++r)
            lmax[r] = fmaxf(fmaxf(s[0][r], s[1][r]), fmaxf(s[2][r], s[3][r]));
        bool need = false;
        #pragma unroll
        for (int r = 0; r < 4; ++r) need |= (lmax[r] > mthr[r]);
        if (__any(need)) {
            float rmax[4], alpha[4];
            #pragma unroll
            for (int r = 0; r < 4; ++r) rmax[r] = lmax[r];
            #pragma unroll
            for (int d = 1; d < 16; d <<= 1) {
                #pragma unroll
                for (int r = 0; r < 4; ++r)
                    rmax[r] = fmaxf(rmax[r], __shfl_xor(rmax[r], d, 64));
            }
            #pragma unroll
            for (int r = 0; r < 4; ++r) {
                float mn = fmaxf(mrun[r], rmax[r]);
                alpha[r] = __builtin_amdgcn_exp2f(mrun[r] - mn);
                mrun[r] = mn;
                mthr[r] = mn + 8.f;
                lpart[r] *= alpha[r];
            }
            #pragma unroll
            for (int i = 0; i < 16; ++i) {
                #pragma unroll
                for (int r = 0; r < 4; ++r) oacc[i][r] *= alpha[r];
            }
        }
        #pragma unroll
        for (int mt = 0; mt < 4; ++mt) {
            #pragma unroll
            for (int r = 0; r < 4; ++r)
                s[mt][r] = __builtin_amdgcn_exp2f(s[mt][r] - mrun[r]);
        }
        #pragma unroll
        for (int r = 0; r < 4; ++r)
            lpart[r] += (s[0][r] + s[1][r]) + (s[2][r] + s[3][r]);

        // ---- 5. P -> LDS packed (column c = lo*4+mt, matches V perm) ----
        #pragma unroll
        for (int r = 0; r < 4; ++r) {
            int2v pk;
            pk[0] = pkbf(s[0][r], s[1][r]);
            pk[1] = pkbf(s[2][r], s[3][r]);
            *(int2v*)(&P_lds[w][hi * 4 + r][lo * 4]) = pk;
        }
        asm volatile("s_waitcnt lgkmcnt(0)" ::: "memory");
        __builtin_amdgcn_sched_barrier(0);
        short8 pa0 = *(const short8*)(&P_lds[w][lo][hi * 8]);
        short8 pa1 = *(const short8*)(&P_lds[w][lo][hi * 8 + 32]);

        // ---- 6. O += P V  (V from swizzled LDS; FULL unroll) ----
        const char* vb = (const char*)&Vlds[cur][0];
        #pragma unroll
        for (int ot = 0; ot < 16; ++ot) {
            const char* rowp = vb + (ot * 16 + lo) * 128;
            short8 bv0 = *(const short8*)(rowp + sw0);
            short8 bv1 = *(const short8*)(rowp + sw1);
            oacc[ot] = __builtin_amdgcn_mfma_f32_16x16x32_bf16(pa0, bv0, oacc[ot], 0, 0, 0);
            oacc[ot] = __builtin_amdgcn_mfma_f32_16x16x32_bf16(pa1, bv1, oacc[ot], 0, 0, 0);
        }

        // ---- 7. fence: stage(t+1) drained, all waves done reading ----
        __builtin_amdgcn_sched_barrier(0);
        asm volatile("s_waitcnt vmcnt(0)" ::: "memory");
        __builtin_amdgcn_s_barrier();
        __builtin_amdgcn_sched_barrier(0);
    }
    // ---- epilogue: reduce per-lane sums, out[b][o][n] = oacc / l ----
    #pragma unroll
    for (int d = 1; d < 16; d <<= 1) {
        #pragma unroll
        for (int r = 0; r < 4; ++r)
            lpart[r] += __shfl_xor(lpart[r], d, 64);
    }
    float inv[4];
    #pragma unroll
    for (int r = 0; r < 4; ++r) inv[r] = 1.f / lpart[r];
    float* ob = out + (size_t)b * DOUT * NN;
    #pragma unroll
    for (int ot = 0; ot < 16; ++ot) {
        #pragma unroll
        for (int r = 0; r < 4; ++r)
            ob[(size_t)(ot * 16 + lo) * NN + (q0 + w * 16 + hi * 4 + r)]
                = oacc[ot][r] * inv[r];
    }
}

// ---------------------------------------------------------------------------
extern "C" void kernel_launch(void* const* d_in, const int* in_sizes, int n_in,
                              void* d_out, int out_size, void* d_ws, size_t ws_size,
                              hipStream_t stream)
{
    const float* x  = (const float*)d_in[0];
    const float* Wq = (const float*)d_in[1];
    const float* Wk = (const float*)d_in[2];
    const float* Wv = (const float*)d_in[3];
    float* out = (float*)d_out;

    short* Qw = (short*)d_ws;                       // B*N*DK bf16  (4 MB)
    short* Kw = Qw + (size_t)NB * NN * DK;          // B*N*DK bf16  (4 MB)
    short* Vw = Kw + (size_t)NB * NN * DK;          // B*DOUT*N bf16 (16 MB, tiled+swizzled)
    // Wb (192 KB bf16) lives at the START of d_out: convw writes it, proj
    // reads it, attn later overwrites all of d_out (stream-ordered -> safe).
    short* Wb = (short*)d_out;

    convw_kernel<<<dim3(JTOT), 256, 0, stream>>>(Wq, Wk, Wv, Wb);
    proj_kernel<<<dim3(NN / 64, NB), 256, 0, stream>>>(x, Wb, Qw, Kw, Vw);
    attn_kernel<<<dim3(NN / 64, NB), 256, 0, stream>>>(Qw, Kw, Vw, out);
}

// Round 9
// 284.237 us; speedup vs baseline: 1.4713x; 1.4713x over previous
//
#include <hip/hip_runtime.h>
#include <hip/hip_bf16.h>

#define NB   8
#define CIN  256
#define NN   4096
#define DK   64
#define DOUT 256
#define KVB  32
#define NT   (NN / KVB)               // 128 KV tiles
#define VTILE_BYTES (DOUT * KVB * 2)  // 16 KB per (b, tile)
#define JTOT 384                      // 64 Q + 64 K + 256 V output channels

typedef float f32x4 __attribute__((ext_vector_type(4)));
typedef short short8 __attribute__((ext_vector_type(8)));
typedef short short4s __attribute__((ext_vector_type(4)));
typedef unsigned int u32;
typedef u32 u32x4 __attribute__((ext_vector_type(4)));

__device__ __forceinline__ short f2bf(float f) {
    unsigned u = __builtin_bit_cast(unsigned, f);
    u = (u + 0x7FFFu + ((u >> 16) & 1u)) >> 16;   // RNE
    return (short)u;
}
// pack two f32 -> (bf16(a) | bf16(b)<<16)  -- plain ops, compiler-scheduled
__device__ __forceinline__ u32 pk2(float a, float b) {
    return (u32)(unsigned short)f2bf(a) | ((u32)(unsigned short)f2bf(b) << 16);
}

__device__ __forceinline__ void gload_lds16(const void* g, void* l) {
    __builtin_amdgcn_global_load_lds(
        (const __attribute__((address_space(1))) void*)g,
        (__attribute__((address_space(3))) void*)l, 16, 0, 0);
}

// V tile format: per (b, kv-tile of 32) a 256(o) x 32(c) bf16 tile.
// Row = 64 B = 4 x 16B chunks; chunk index XOR ((o>>1)&3)  -> 2-way banks (free).
// Column permutation: column c holds tile-local n with c = (n&15)*2 + (n>>4),
// matching attn's packed P column order c = lo*2 + mt (both operands permuted
// identically -> PV contraction unchanged).

// ---------------------------------------------------------------------------
// convw: pack Wq (x 0.125*log2e, folds temperature + exp->exp2), Wk, Wv into
// one bf16 matrix Wb[384][256]. grid 384, block 256.
// ---------------------------------------------------------------------------
__global__ __launch_bounds__(256) void convw_kernel(
    const float* __restrict__ Wq, const float* __restrict__ Wk,
    const float* __restrict__ Wv, short* __restrict__ Wb)
{
    const int j = blockIdx.x;
    const int c = threadIdx.x;
    float v;
    if (j < 64)       v = Wq[j * CIN + c] * 0.18033688011f;   // 0.125*log2(e)
    else if (j < 128) v = Wk[(j - 64) * CIN + c];
    else              v = Wv[(j - 128) * CIN + c];
    Wb[(size_t)j * CIN + c] = f2bf(v);
}

// ---------------------------------------------------------------------------
// Projection via MFMA: Y[j][n] = sum_c Wb[j][c] * x[b][c][n0+n], 64 n x 384 j
// per block. x tile staged to LDS bf16, transposed [n][c] with chunk-XOR
// swizzle ^(n&7). A = Wb rows (global short8), B = x cols (LDS short8).
// D: col=lane&15=n, row=4*hi+r=j.  Q/K: packed short4 stores.
// V: packed 4B stores into the permuted+swizzled 256x32 tiles (2 per block).
// grid (NN/64, NB), block 256 (4 waves x 96 j each).
// ---------------------------------------------------------------------------
__global__ __launch_bounds__(256) void proj_kernel(
    const float* __restrict__ x, const short* __restrict__ Wb,
    short* __restrict__ Qw, short* __restrict__ Kw, short* __restrict__ Vw)
{
    __shared__ short Xt[64][256];            // 32 KB, rows swizzled
    const int t  = threadIdx.x;
    const int nt = blockIdx.x;               // 64-col n-tile (= 2 V tiles)
    const int b  = blockIdx.y;
    const int n0 = nt * 64;
    const int w  = t >> 6;
    const int l  = t & 63;
    const int hi = l >> 4, lo = l & 15;

    // ---- stage x tile: thread (l, cg=w) loads 64 c for n = n0+l ----
    {
        const float* xs = x + (size_t)b * CIN * NN + (size_t)(w * 64) * NN + n0 + l;
        #pragma unroll
        for (int c8 = 0; c8 < 8; ++c8) {
            float f[8];
            #pragma unroll
            for (int i = 0; i < 8; ++i)
                f[i] = xs[(size_t)(c8 * 8 + i) * NN];
            u32x4 pk;
            #pragma unroll
            for (int j = 0; j < 4; ++j) pk[j] = pk2(f[2 * j], f[2 * j + 1]);
            const int c0 = w * 64 + c8 * 8;
            *(u32x4*)((char*)&Xt[0][0] + l * 512 + ((((c0 >> 3) ^ (l & 7)) << 4)))
                = pk;
        }
    }
    __syncthreads();

    const int wj0 = w * 96;                  // wave's j range (6 tiles of 16)
    f32x4 acc[6][4];
    #pragma unroll
    for (int jt = 0; jt < 6; ++jt)
        #pragma unroll
        for (int ntl = 0; ntl < 4; ++ntl) acc[jt][ntl] = f32x4{0.f, 0.f, 0.f, 0.f};

    #pragma unroll 2
    for (int kb = 0; kb < 8; ++kb) {
        short8 aw[6], bx[4];
        #pragma unroll
        for (int jt = 0; jt < 6; ++jt)
            aw[jt] = *(const short8*)(Wb + (size_t)(wj0 + jt * 16 + lo) * CIN
                                         + kb * 32 + hi * 8);
        #pragma unroll
        for (int ntl = 0; ntl < 4; ++ntl) {
            const int n = ntl * 16 + lo;
            bx[ntl] = *(const short8*)((char*)&Xt[0][0] + n * 512
                                       + ((((kb * 4 + hi) ^ (n & 7)) << 4)));
        }
        #pragma unroll
        for (int jt = 0; jt < 6; ++jt)
            #pragma unroll
            for (int ntl = 0; ntl < 4; ++ntl)
                acc[jt][ntl] = __builtin_amdgcn_mfma_f32_16x16x32_bf16(
                    aw[jt], bx[ntl], acc[jt][ntl], 0, 0, 0);
    }

    // ---- epilogue ----
    char* vt0 = (char*)(Vw + (size_t)b * DOUT * NN)
              + (size_t)(nt * 2) * VTILE_BYTES;
    #pragma unroll
    for (int jt = 0; jt < 6; ++jt) {
        const int jbase = wj0 + jt * 16;     // wave-uniform dest selector
        if (jbase < 128) {                   // Q or K: packed short4 per ntl
            #pragma unroll
            for (int ntl = 0; ntl < 4; ++ntl) {
                const f32x4 a = acc[jt][ntl];
                const int n = ntl * 16 + lo;
                short4s pk;
                #pragma unroll
                for (int r = 0; r < 4; ++r) pk[r] = f2bf(a[r]);
                short* base = (jbase < 64)
                    ? (Qw + (size_t)b * NN * DK + (size_t)(n0 + n) * DK + jbase)
                    : (Kw + (size_t)b * NN * DK + (size_t)(n0 + n) * DK + (jbase - 64));
                *(short4s*)(base + hi * 4) = pk;
            }
        } else {                             // V: packed 4B stores, 2 tiles
            #pragma unroll
            for (int r = 0; r < 4; ++r) {
                const int o = jbase - 128 + hi * 4 + r;
                // cols lo*2, lo*2+1 -> chunk lo>>2 (^ swz), byte (lo&3)*4
                const int off = o * 64 + ((((lo >> 2) ^ ((o >> 1) & 3)) << 4))
                              + ((lo & 3) << 2);
                *(u32*)(vt0 + off)               = pk2(acc[jt][0][r], acc[jt][1][r]);
                *(u32*)(vt0 + VTILE_BYTES + off) = pk2(acc[jt][2][r], acc[jt][3][r]);
            }
        }
    }
}

// ---------------------------------------------------------------------------
// Flash attention: per block 64 q-rows, 4 waves x 16 rows, KVBLK=32.
// V tile double-buffered in LDS (global_load_lds of pre-swizzled+permuted
// tiles), 2-phase pipeline: K-loads -> STAGE(t+1) -> QK -> softmax (exp2,
// defer-max THR=8, deferred per-lane sum) -> packed-P roundtrip -> PV ->
// vmcnt(0)+barrier.  grid (NN/64, NB), block 256, 4 blocks/CU target.
// NOTE: PV loop MUST be fully unrolled (rule #20: runtime-indexed oacc ->
// scratch; round-2 showed 2.9 GB scratch writes).
// ---------------------------------------------------------------------------
__global__ __launch_bounds__(256, 4) void attn_kernel(
    const short* __restrict__ Q, const short* __restrict__ K,
    const short* __restrict__ Vt, float* __restrict__ out)
{
    __shared__ short Vlds[2][DOUT * KVB];    // 2 x 16 KB
    __shared__ short P_lds[4][16][40];       // rows 80 B (16B-aligned reads)
    const int b  = blockIdx.y;
    const int q0 = blockIdx.x * 64;
    const int w  = threadIdx.x >> 6;
    const int l  = threadIdx.x & 63;
    const int hi = l >> 4, lo = l & 15;

    const short* Qb = Q  + (size_t)b * NN * DK;
    const short* Kb = K  + (size_t)b * NN * DK;
    const char*  Vbase = (const char*)(Vt + (size_t)b * DOUT * NN);

    // Q A-fragments: lane -> row = lane&15, k = (lane>>4)*8 + j (+32 per step)
    const int qrow = q0 + w * 16 + lo;
    const short8 aq0 = *(const short8*)(Qb + (size_t)qrow * DK + hi * 8);
    const short8 aq1 = *(const short8*)(Qb + (size_t)qrow * DK + hi * 8 + 32);

    // per-lane swizzled chunk offset for PV ds_reads: chunk hi ^ ((o>>1)&3),
    // (o>>1)&3 == (lo>>1)&3 since o = ot*16+lo
    const int swv = (hi ^ ((lo >> 1) & 3)) << 4;

    f32x4 oacc[16];
    #pragma unroll
    for (int i = 0; i < 16; ++i) oacc[i] = f32x4{0.f, 0.f, 0.f, 0.f};
    float mrun[4], lpart[4];
    #pragma unroll
    for (int r = 0; r < 4; ++r) { mrun[r] = -1e30f; lpart[r] = 0.f; }

    // ---- prologue: stage tile 0 into buf 0 (16 chunks of 1 KB) ----
    #pragma unroll
    for (int kk = 0; kk < 4; ++kk) {
        const int c = kk * 4 + w;
        gload_lds16(Vbase + c * 1024 + l * 16, (char*)&Vlds[0][0] + c * 1024);
    }
    asm volatile("s_waitcnt vmcnt(0)" ::: "memory");
    __builtin_amdgcn_s_barrier();
    __builtin_amdgcn_sched_barrier(0);

    for (int t = 0; t < NT; ++t) {
        const int cur = t & 1;
        const int m0  = t * KVB;

        // ---- 1. K loads for this tile (issued BEFORE stage: FIFO vmcnt) ----
        short8 bk0[2], bk1[2];
        #pragma unroll
        for (int mt = 0; mt < 2; ++mt) {
            const short* kr = Kb + (size_t)(m0 + mt * 16 + lo) * DK + hi * 8;
            bk0[mt] = *(const short8*)(kr);
            bk1[mt] = *(const short8*)(kr + 32);
        }
        __builtin_amdgcn_sched_barrier(0);

        // ---- 2. STAGE V(t+1) into the other buffer ----
        {
            const int tn = (t + 1 < NT) ? t + 1 : NT - 1;
            const char* vtile = Vbase + (size_t)tn * VTILE_BYTES;
            #pragma unroll
            for (int kk = 0; kk < 4; ++kk) {
                const int c = kk * 4 + w;
                gload_lds16(vtile + c * 1024 + l * 16,
                            (char*)&Vlds[cur ^ 1][0] + c * 1024);
            }
        }
        __builtin_amdgcn_sched_barrier(0);

        // ---- 3. S = Q K^T ----
        f32x4 s[2];
        #pragma unroll
        for (int mt = 0; mt < 2; ++mt) {
            f32x4 acc = {0.f, 0.f, 0.f, 0.f};
            acc = __builtin_amdgcn_mfma_f32_16x16x32_bf16(aq0, bk0[mt], acc, 0, 0, 0);
            acc = __builtin_amdgcn_mfma_f32_16x16x32_bf16(aq1, bk1[mt], acc, 0, 0, 0);
            s[mt] = acc;
        }

        // ---- 4. softmax: defer-max (THR=8); rescale only when max grows ----
        float lmax[4];
        #pragma unroll
        for (int r = 0; r < 4; ++r) lmax[r] = fmaxf(s[0][r], s[1][r]);
        bool need = false;
        #pragma unroll
        for (int r = 0; r < 4; ++r) need |= (lmax[r] - mrun[r] > 8.f);
        if (__any(need)) {
            float rmax[4], alpha[4];
            #pragma unroll
            for (int r = 0; r < 4; ++r) rmax[r] = lmax[r];
            #pragma unroll
            for (int d = 1; d < 16; d <<= 1) {
                #pragma unroll
                for (int r = 0; r < 4; ++r)
                    rmax[r] = fmaxf(rmax[r], __shfl_xor(rmax[r], d, 64));
            }
            #pragma unroll
            for (int r = 0; r < 4; ++r) {
                float mn = fmaxf(mrun[r], rmax[r]);
                alpha[r] = __builtin_amdgcn_exp2f(mrun[r] - mn);
                mrun[r] = mn;
                lpart[r] *= alpha[r];
            }
            #pragma unroll
            for (int i = 0; i < 16; ++i) {
                #pragma unroll
                for (int r = 0; r < 4; ++r) oacc[i][r] *= alpha[r];
            }
        }
        #pragma unroll
        for (int mt = 0; mt < 2; ++mt) {
            #pragma unroll
            for (int r = 0; r < 4; ++r)
                s[mt][r] = __builtin_amdgcn_exp2f(s[mt][r] - mrun[r]);
        }
        #pragma unroll
        for (int r = 0; r < 4; ++r)
            lpart[r] += s[0][r] + s[1][r];

        // ---- 5. P -> LDS packed (col c = lo*2+mt, matches V tile perm) ----
        #pragma unroll
        for (int r = 0; r < 4; ++r)
            *(u32*)(&P_lds[w][hi * 4 + r][lo * 2]) = pk2(s[0][r], s[1][r]);
        asm volatile("s_waitcnt lgkmcnt(0)" ::: "memory");
        __builtin_amdgcn_sched_barrier(0);
        short8 pa = *(const short8*)(&P_lds[w][lo][hi * 8]);

        // ---- 6. O += P V  (V from swizzled LDS; FULL unroll) ----
        const char* vb = (const char*)&Vlds[cur][0];
        #pragma unroll
        for (int ot = 0; ot < 16; ++ot) {
            short8 bv = *(const short8*)(vb + (ot * 16 + lo) * 64 + swv);
            oacc[ot] = __builtin_amdgcn_mfma_f32_16x16x32_bf16(pa, bv, oacc[ot], 0, 0, 0);
        }

        // ---- 7. fence: stage(t+1) drained, all waves done reading ----
        __builtin_amdgcn_sched_barrier(0);
        asm volatile("s_waitcnt vmcnt(0)" ::: "memory");
        __builtin_amdgcn_s_barrier();
        __builtin_amdgcn_sched_barrier(0);
    }
    // ---- epilogue: reduce per-lane sums, out[b][o][n] = oacc / l ----
    #pragma unroll
    for (int d = 1; d < 16; d <<= 1) {
        #pragma unroll
        for (int r = 0; r < 4; ++r)
            lpart[r] += __shfl_xor(lpart[r], d, 64);
    }
    float inv[4];
    #pragma unroll
    for (int r = 0; r < 4; ++r) inv[r] = 1.f / lpart[r];
    float* ob = out + (size_t)b * DOUT * NN;
    #pragma unroll
    for (int ot = 0; ot < 16; ++ot) {
        #pragma unroll
        for (int r = 0; r < 4; ++r)
            ob[(size_t)(ot * 16 + lo) * NN + (q0 + w * 16 + hi * 4 + r)]
                = oacc[ot][r] * inv[r];
    }
}

// ---------------------------------------------------------------------------
extern "C" void kernel_launch(void* const* d_in, const int* in_sizes, int n_in,
                              void* d_out, int out_size, void* d_ws, size_t ws_size,
                              hipStream_t stream)
{
    const float* x  = (const float*)d_in[0];
    const float* Wq = (const float*)d_in[1];
    const float* Wk = (const float*)d_in[2];
    const float* Wv = (const float*)d_in[3];
    float* out = (float*)d_out;

    short* Qw = (short*)d_ws;                       // B*N*DK bf16  (4 MB)
    short* Kw = Qw + (size_t)NB * NN * DK;          // B*N*DK bf16  (4 MB)
    short* Vw = Kw + (size_t)NB * NN * DK;          // B*DOUT*N bf16 (16 MB, tiled+swizzled)
    // Wb (192 KB bf16) lives at the START of d_out: convw writes it, proj
    // reads it, attn later overwrites all of d_out (stream-ordered -> safe).
    short* Wb = (short*)d_out;

    convw_kernel<<<dim3(JTOT), 256, 0, stream>>>(Wq, Wk, Wv, Wb);
    proj_kernel<<<dim3(NN / 64, NB), 256, 0, stream>>>(x, Wb, Qw, Kw, Vw);
    attn_kernel<<<dim3(NN / 64, NB), 256, 0, stream>>>(Qw, Kw, Vw, out);
}